// Round 6
// baseline (456.962 us; speedup 1.0000x reference)
//
#include <hip/hip_runtime.h>
#include <type_traits>

#define N_TOK 65536
#define K_CODE 8192
#define D_DIM 64

constexpr float DECAY = 0.9f;
constexpr float OMD = 0.1f;   // 1 - DECAY
constexpr float EPS = 1e-5f;

// ---- output layout (floats), per reference return order ----
constexpr int OUT_QE = 0;
constexpr int OUT_W  = 1;
constexpr int OUT_CS = 1 + K_CODE * D_DIM;
constexpr int OUT_EA = OUT_CS + K_CODE;

// ---- workspace layout (floats) ----
constexpr int WS_QE     = 0;
constexpr int WS_NSUM   = 1;
constexpr int WS_COUNTS = 16;
constexpr int WS_EMBSUM = WS_COUNTS + K_CODE;
constexpr int WS_CNORM  = WS_EMBSUM + K_CODE * D_DIM;   // fp32 ||c||^2 [K]
constexpr int WS_WHI    = WS_CNORM + K_CODE;            // ushort[K*64] bf16 hi
constexpr int WS_WLO    = WS_WHI + K_CODE * D_DIM / 2;  // ushort[K*64] bf16 lo
constexpr int WS_ZERO   = WS_CNORM;                     // floats to memset

typedef __attribute__((ext_vector_type(16))) float floatx16;
typedef __attribute__((ext_vector_type(8)))  short short8;
typedef __attribute__((ext_vector_type(8)))  __bf16 bf16x8;

// SFINAE hedge: mfma bf16 builtin takes v8bf16 on newer clang, v8i16 on older.
template <typename T, typename = void> struct mfma_takes : std::false_type {};
template <typename T>
struct mfma_takes<T, std::void_t<decltype(__builtin_amdgcn_mfma_f32_32x32x16_bf16(
    std::declval<T>(), std::declval<T>(), std::declval<floatx16>(), 0, 0, 0))>>
    : std::true_type {};

__device__ __forceinline__ floatx16 MFMA(short8 a, short8 b, floatx16 c) {
  if constexpr (mfma_takes<bf16x8>::value) {
    return __builtin_amdgcn_mfma_f32_32x32x16_bf16(
        __builtin_bit_cast(bf16x8, a), __builtin_bit_cast(bf16x8, b), c, 0, 0, 0);
  } else {
    return __builtin_amdgcn_mfma_f32_32x32x16_bf16(a, b, c, 0, 0, 0);
  }
}

__device__ __forceinline__ unsigned short bf16rne(float x) {
  unsigned int u = __float_as_uint(x);
  return (unsigned short)((u + 0x7FFFu + ((u >> 16) & 1u)) >> 16);
}

// ---------------------------------------------------------------------------
// Split W into bf16 hi/lo; exact fp32 ||c||^2. One wave per code.
__global__ void vq_prep(const float* __restrict__ w, float* __restrict__ ws) {
  const int tid = threadIdx.x;
  const int lane = tid & 63;
  const int k = blockIdx.x * 4 + (tid >> 6);
  const float v = w[(size_t)k * D_DIM + lane];
  const unsigned short h = bf16rne(v);
  const float hf = __uint_as_float((unsigned int)h << 16);
  const unsigned short l = bf16rne(v - hf);
  unsigned short* whi = (unsigned short*)(ws + WS_WHI);
  unsigned short* wlo = (unsigned short*)(ws + WS_WLO);
  whi[(size_t)k * D_DIM + lane] = h;
  wlo[(size_t)k * D_DIM + lane] = l;
  float s = v * v;
#pragma unroll
  for (int m = 32; m >= 1; m >>= 1) s += __shfl_xor(s, m);
  if (lane == 0) ws[WS_CNORM + k] = s;
}

// ---------------------------------------------------------------------------
// Fused split-bf16 MFMA distance + argmin + segment-sum scatter.
// Block = 256 thr = 4 waves = 2 token-groups(32 tok) x 2 code-halves(4096).
// Grid = 1024 blocks = 4 blocks/CU, 16 waves/CU = 4 waves/SIMD.
// Per code-half an LDS stream of 32-code double-buffered stages, stride-72
// rows (R2's measured-0-conflict pattern). 128 stages, 128 barriers; barrier
// drains hidden by 3 co-resident blocks. Per stage per wave: 12 MFMAs
// (zh*wh + zl*wh + zh*wl over 4 k-steps), single acc chain (4 waves/SIMD
// covers the latency). d = ||c||^2 - 2 z.c via VALU fma.
__global__ __launch_bounds__(256, 4) void vq_argmin(
    const float* __restrict__ z, float* __restrict__ ws)
{
  __shared__ __align__(16) unsigned short Wbuf[2][2][2][32 * 72]; // [half][buf][plane]
  __shared__ float mind_s[2][64];
  __shared__ int   tok_s[2][64];

  const int tid  = threadIdx.x;
  const int w    = tid >> 6;    // wave 0..3
  const int lane = tid & 63;
  const int m    = lane & 31;   // A row (token) / B col (code) in tile
  const int h    = lane >> 5;   // k-half selector
  const int tg   = w & 1;       // token group (32 tokens)
  const int hw   = w >> 1;      // code half (4096 codes)
  const int tb   = blockIdx.x * 64;

  const unsigned short* whi = (const unsigned short*)(ws + WS_WHI);
  const unsigned short* wlo = (const unsigned short*)(ws + WS_WLO);
  const float* cnorm_g = ws + WS_CNORM;

  // ---- A fragments: bf16 hi/lo split of this wave's 32 z rows ----
  short8 ah[4], al[4];
  float znorm = 0.f;
  {
    const float* zrow = z + (size_t)(tb + tg * 32 + m) * D_DIM + 8 * h;
#pragma unroll
    for (int s4 = 0; s4 < 4; ++s4) {
      const float4 v0 = *(const float4*)(zrow + 16 * s4);
      const float4 v1 = *(const float4*)(zrow + 16 * s4 + 4);
      const float vals[8] = {v0.x, v0.y, v0.z, v0.w, v1.x, v1.y, v1.z, v1.w};
#pragma unroll
      for (int j = 0; j < 8; ++j) {
        const float x = vals[j];
        znorm += x * x;
        const unsigned short hb = bf16rne(x);
        const float hf = __uint_as_float((unsigned int)hb << 16);
        const unsigned short lb = bf16rne(x - hf);
        ah[s4][j] = (short)hb;
        al[s4][j] = (short)lb;
      }
    }
    znorm += __shfl_xor(znorm, 32);   // other k-half of the same token row
  }

  float minv[16];
  int   mini[16];
#pragma unroll
  for (int r = 0; r < 16; ++r) { minv[r] = 3.4e38f; mini[r] = 0; }

  // ---- staging: per stage 2 halves x 2 planes x 32 rows x 8 granules(16B).
  // 256 threads: one granule per (half,plane) each. Coalesced 16B loads.
  const int srow = tid >> 3;    // 0..31
  const int scol = tid & 7;     // 0..7
  uint4 sl[4];
  auto stageLoad = [&](int s) {
    const size_t off0 = ((size_t)(s * 32 + srow)) * D_DIM + scol * 8;
    const size_t off1 = ((size_t)(4096 + s * 32 + srow)) * D_DIM + scol * 8;
    sl[0] = *(const uint4*)(whi + off0);
    sl[1] = *(const uint4*)(wlo + off0);
    sl[2] = *(const uint4*)(whi + off1);
    sl[3] = *(const uint4*)(wlo + off1);
  };
  auto stageWrite = [&](int b) {
    const int loff = srow * 72 + scol * 8;
    *(uint4*)&Wbuf[0][b][0][loff] = sl[0];
    *(uint4*)&Wbuf[0][b][1][loff] = sl[1];
    *(uint4*)&Wbuf[1][b][0][loff] = sl[2];
    *(uint4*)&Wbuf[1][b][1][loff] = sl[3];
  };

  stageLoad(0);
  stageWrite(0);
  __syncthreads();

  const floatx16 kZero = {};

  for (int s = 0; s < 128; ++s) {
    const int b = s & 1;
    const float cn = cnorm_g[hw * 4096 + s * 32 + m];  // L2-hot, issued early
    if (s + 1 < 128) stageLoad(s + 1);                 // overlaps compute

    short8 bh[4], bl[4];
#pragma unroll
    for (int s4 = 0; s4 < 4; ++s4) {
      const int off = m * 72 + (2 * s4 + h) * 8;       // proven 0-conflict
      bh[s4] = *(const short8*)&Wbuf[hw][b][0][off];
      bl[s4] = *(const short8*)&Wbuf[hw][b][1][off];
    }

    floatx16 acc = kZero;
#pragma unroll
    for (int s4 = 0; s4 < 4; ++s4) acc = MFMA(ah[s4], bh[s4], acc);  // zh.ch
#pragma unroll
    for (int s4 = 0; s4 < 4; ++s4) acc = MFMA(al[s4], bh[s4], acc);  // zl.ch
#pragma unroll
    for (int s4 = 0; s4 < 4; ++s4) acc = MFMA(ah[s4], bl[s4], acc);  // zh.cl

    // dist = ||c||^2 - 2 z.c ; code ascending + strict '<' keeps first-min
    const int code = hw * 4096 + s * 32 + m;
#pragma unroll
    for (int r = 0; r < 16; ++r) {
      const float d = __builtin_fmaf(-2.f, acc[r], cn);
      const bool lt = d < minv[r];
      minv[r] = lt ? d : minv[r];
      mini[r] = lt ? code : mini[r];
    }

    if (s + 1 < 128) stageWrite(b ^ 1);
    __syncthreads();
  }

  // ---- reduce over the 32 lanes (cols) per row; first-index tie-break ----
#pragma unroll
  for (int r = 0; r < 16; ++r) {
#pragma unroll
    for (int mm = 1; mm < 32; mm <<= 1) {
      const float ov = __shfl_xor(minv[r], mm);
      const int   oi = __shfl_xor(mini[r], mm);
      if (ov < minv[r] || (ov == minv[r] && oi < mini[r])) { minv[r] = ov; mini[r] = oi; }
    }
  }

  // C/D layout: row = (r&3) + 8*(r>>2) + 4*h. One writer lane per row.
#pragma unroll
  for (int r = 0; r < 16; ++r) {
    const int mr = (r & 3) + 8 * (r >> 2) + 4 * h;
    if (m == mr) {
      tok_s[hw][tg * 32 + mr]  = mini[r];
      mind_s[hw][tg * 32 + mr] = minv[r] + znorm;   // full dist for qe
    }
  }
  __syncthreads();

  float* counts = ws + WS_COUNTS;
  float* embsum = ws + WS_EMBSUM;

  // merge code-halves (h0 codes < h1 codes: strict '<' keeps first-index),
  // then qe partial + counts
  if (tid < 64) {
    const float d0 = mind_s[0][tid], d1 = mind_s[1][tid];
    const int   i0 = tok_s[0][tid],  i1 = tok_s[1][tid];
    const bool t1 = d1 < d0;
    const float dm = t1 ? d1 : d0;
    const int   im = t1 ? i1 : i0;
    tok_s[0][tid] = im;
    float qe = dm;
#pragma unroll
    for (int mm = 32; mm >= 1; mm >>= 1) qe += __shfl_xor(qe, mm);
    if (tid == 0) atomicAdd(ws + WS_QE, qe);
    atomicAdd(&counts[im], 1.0f);
  }
  __syncthreads();

  // segment-sum of z: wave-coalesced atomics (64 consecutive floats/instr)
#pragma unroll 4
  for (int t = 0; t < 16; ++t) {
    const int row = w * 16 + t;
    const int tk = tok_s[0][row];
    const float zv = z[(size_t)(tb + row) * D_DIM + lane];
    atomicAdd(&embsum[(size_t)tk * D_DIM + lane], zv);
  }
}

// ---------------------------------------------------------------------------
__global__ void vq_finalize_cs(const float* __restrict__ cluster_size,
                               float* __restrict__ ws, float* __restrict__ out)
{
  const int k = blockIdx.x * 256 + threadIdx.x;
  const float ncs = cluster_size[k] * DECAY + OMD * ws[WS_COUNTS + k];
  out[OUT_CS + k] = ncs;
  float s = ncs;
#pragma unroll
  for (int m = 32; m >= 1; m >>= 1) s += __shfl_xor(s, m);
  __shared__ float part[4];
  if ((threadIdx.x & 63) == 0) part[threadIdx.x >> 6] = s;
  __syncthreads();
  if (threadIdx.x == 0) {
    atomicAdd(ws + WS_NSUM, part[0] + part[1] + part[2] + part[3]);
    if (blockIdx.x == 0) out[OUT_QE] = ws[WS_QE] * (1.0f / N_TOK);
  }
}

__global__ void vq_finalize_w(const float* __restrict__ embed_avg,
                              const float* __restrict__ ws, float* __restrict__ out)
{
  const int idx = blockIdx.x * 256 + threadIdx.x;
  const int k = idx >> 6;
  const float nea = embed_avg[idx] * DECAY + OMD * ws[WS_EMBSUM + idx];
  out[OUT_EA + idx] = nea;
  const float n = ws[WS_NSUM];
  const float ncs = out[OUT_CS + k];
  const float sm = (ncs + EPS) / (n + K_CODE * EPS) * n;
  out[OUT_W + idx] = nea / sm;
}

// ---------------------------------------------------------------------------
extern "C" void kernel_launch(void* const* d_in, const int* in_sizes, int n_in,
                              void* d_out, int out_size, void* d_ws, size_t ws_size,
                              hipStream_t stream) {
  const float* z  = (const float*)d_in[0];
  const float* w  = (const float*)d_in[1];
  const float* cs = (const float*)d_in[2];
  const float* ea = (const float*)d_in[3];
  float* out = (float*)d_out;
  float* ws  = (float*)d_ws;

  (void)hipMemsetAsync(d_ws, 0, (size_t)WS_ZERO * sizeof(float), stream);

  vq_prep<<<K_CODE / 4, 256, 0, stream>>>(w, ws);
  vq_argmin<<<N_TOK / 64, 256, 0, stream>>>(z, ws);
  vq_finalize_cs<<<K_CODE / 256, 256, 0, stream>>>(cs, ws, out);
  vq_finalize_w<<<K_CODE * D_DIM / 256, 256, 0, stream>>>(ea, ws, out);
}

// Round 7
// 282.168 us; speedup vs baseline: 1.6195x; 1.6195x over previous
//
#include <hip/hip_runtime.h>
#include <type_traits>

#define N_TOK 65536
#define K_CODE 8192
#define D_DIM 64

constexpr float DECAY = 0.9f;
constexpr float OMD = 0.1f;   // 1 - DECAY
constexpr float EPS = 1e-5f;

// ---- output layout (floats), per reference return order ----
constexpr int OUT_QE = 0;
constexpr int OUT_W  = 1;
constexpr int OUT_CS = 1 + K_CODE * D_DIM;
constexpr int OUT_EA = OUT_CS + K_CODE;

// ---- workspace layout (floats) ----
constexpr int WS_QE     = 0;
constexpr int WS_NSUM   = 1;
constexpr int WS_COUNTS = 16;
constexpr int WS_EMBSUM = WS_COUNTS + K_CODE;
constexpr int WS_CNORM  = WS_EMBSUM + K_CODE * D_DIM;   // fp32 ||c||^2 + 64 [K]
constexpr int WS_WHI    = WS_CNORM + K_CODE;            // ushort[K*64] bf16 hi, XOR-swizzled
constexpr int WS_WLO    = WS_WHI + K_CODE * D_DIM / 2;  // ushort[K*64] bf16 lo, XOR-swizzled
constexpr int WS_ZERO   = WS_CNORM;                     // floats to memset

typedef __attribute__((ext_vector_type(16))) float floatx16;
typedef __attribute__((ext_vector_type(8)))  short short8;
typedef __attribute__((ext_vector_type(8)))  __bf16 bf16x8;

// SFINAE hedge: mfma bf16 builtin takes v8bf16 on newer clang, v8i16 on older.
template <typename T, typename = void> struct mfma_takes : std::false_type {};
template <typename T>
struct mfma_takes<T, std::void_t<decltype(__builtin_amdgcn_mfma_f32_32x32x16_bf16(
    std::declval<T>(), std::declval<T>(), std::declval<floatx16>(), 0, 0, 0))>>
    : std::true_type {};

__device__ __forceinline__ floatx16 MFMA(short8 a, short8 b, floatx16 c) {
  if constexpr (mfma_takes<bf16x8>::value) {
    return __builtin_amdgcn_mfma_f32_32x32x16_bf16(
        __builtin_bit_cast(bf16x8, a), __builtin_bit_cast(bf16x8, b), c, 0, 0, 0);
  } else {
    return __builtin_amdgcn_mfma_f32_32x32x16_bf16(a, b, c, 0, 0, 0);
  }
}

__device__ __forceinline__ unsigned short bf16rne(float x) {
  unsigned int u = __float_as_uint(x);
  return (unsigned short)((u + 0x7FFFu + ((u >> 16) & 1u)) >> 16);
}

// async global->LDS 16B DMA (dest = wave-uniform base + lane*16)
__device__ __forceinline__ void gload_lds16(const unsigned short* g, unsigned short* l) {
#if defined(__has_builtin) && __has_builtin(__builtin_amdgcn_global_load_lds)
  typedef __attribute__((address_space(1))) void gvoid;
  typedef __attribute__((address_space(3))) void lvoid;
  __builtin_amdgcn_global_load_lds((gvoid*)g, (lvoid*)l, 16, 0, 0);
#else
  *(uint4*)l = *(const uint4*)g;   // sync fallback, correctness-equal
#endif
}

// ---------------------------------------------------------------------------
// Split W into bf16 hi/lo, stored XOR-SWIZZLED (granule g -> g^(k&7), stride
// 64 shorts) so global_load_lds's linear copy produces a conflict-free LDS
// layout. Also store ||c||^2 + 64 (offset folded for the packed-key trick).
__global__ void vq_prep(const float* __restrict__ w, float* __restrict__ ws) {
  const int tid = threadIdx.x;
  const int d = tid & 63;                 // dim
  const int k = blockIdx.x * 4 + (tid >> 6);
  const float v = w[(size_t)k * D_DIM + d];
  const unsigned short h = bf16rne(v);
  const float hf = __uint_as_float((unsigned int)h << 16);
  const unsigned short l = bf16rne(v - hf);
  unsigned short* whi = (unsigned short*)(ws + WS_WHI);
  unsigned short* wlo = (unsigned short*)(ws + WS_WLO);
  const int pos = k * D_DIM + (((d >> 3) ^ (k & 7)) * 8) + (d & 7);
  whi[pos] = h;
  wlo[pos] = l;
  float s = v * v;
#pragma unroll
  for (int m = 32; m >= 1; m >>= 1) s += __shfl_xor(s, m);
  if (d == 0) ws[WS_CNORM + k] = s + 64.0f;
}

// ---------------------------------------------------------------------------
// Fused split-bf16 MFMA distance + argmin + segment-sum scatter.
// Block = 4 waves = 2 token-groups x 2 code-halves; 128 tokens/block,
// 512 blocks, 2 blocks/CU, 2 waves/SIMD. Each wave: 2 A-sets (64 tokens) vs
// its 4096-code half in 64-code double-buffered LDS stages (global_load_lds).
// Per 32-code chunk: 24 MFMAs per B-read pair; epilogue 3 VALU/element via
// packed key = float(cn+64-2z.c) with low 8 mantissa bits = chunk index
// (gives first-occurrence tie-break and kills the index registers).
__global__ __launch_bounds__(256, 2) void vq_argmin(
    const float* __restrict__ z, float* __restrict__ ws)
{
  __shared__ __align__(16) unsigned short Wbuf[2][2][2][64 * 64]; // [half][buf][plane]
  __shared__ float mind_s[2][128];
  __shared__ int   tok_s[2][128];

  const int tid  = threadIdx.x;
  const int w    = tid >> 6;    // wave 0..3
  const int lane = tid & 63;
  const int m    = lane & 31;   // A row (token) / B col (code) in tile
  const int h    = lane >> 5;   // k-half selector
  const int tg   = w & 1;       // token group (64 tokens)
  const int hw   = w >> 1;      // code half (4096 codes)
  const int tb   = blockIdx.x * 128;

  const unsigned short* whi = (const unsigned short*)(ws + WS_WHI);
  const unsigned short* wlo = (const unsigned short*)(ws + WS_WLO);
  const float* cnorm_g = ws + WS_CNORM;

  // ---- A fragments: bf16 hi/lo split of 2 sets of 32 z rows each ----
  short8 ah[2][4], al[2][4];
  float znorm[2];
#pragma unroll
  for (int set = 0; set < 2; ++set) {
    const float* zrow = z + (size_t)(tb + tg * 64 + set * 32 + m) * D_DIM + 8 * h;
    float zn = 0.f;
#pragma unroll
    for (int s4 = 0; s4 < 4; ++s4) {
      const float4 v0 = *(const float4*)(zrow + 16 * s4);
      const float4 v1 = *(const float4*)(zrow + 16 * s4 + 4);
      const float vals[8] = {v0.x, v0.y, v0.z, v0.w, v1.x, v1.y, v1.z, v1.w};
#pragma unroll
      for (int j = 0; j < 8; ++j) {
        const float x = vals[j];
        zn += x * x;
        const unsigned short hb = bf16rne(x);
        const float hf = __uint_as_float((unsigned int)hb << 16);
        const unsigned short lb = bf16rne(x - hf);
        ah[set][s4][j] = (short)hb;
        al[set][s4][j] = (short)lb;
      }
    }
    zn += __shfl_xor(zn, 32);   // other k-half of the same token row
    znorm[set] = zn;
  }

  float kmin[2][16];
#pragma unroll
  for (int set = 0; set < 2; ++set)
#pragma unroll
    for (int r = 0; r < 16; ++r) kmin[set][r] = 3.4e38f;

  // ---- prefetch: wave w DMAs (half=hw, plane=w&1), 8 KB/stage, 8 instrs ----
  const unsigned short* gplane = ((w & 1) ? wlo : whi) + (size_t)hw * 4096 * D_DIM + lane * 8;
  unsigned short* lplane = &Wbuf[hw][0][w & 1][0];
  auto issueStage = [&](int s, int b) {
    const unsigned short* src = gplane + (size_t)s * (64 * D_DIM);
    unsigned short* dst = lplane + b * (2 * 64 * 64);   // [buf] stride in shorts
#pragma unroll
    for (int i = 0; i < 8; ++i)
      gload_lds16(src + i * 512, dst + i * 512);
  };

  // precomputed per-lane B read offsets (shorts)
  int xoff[4];
#pragma unroll
  for (int s4 = 0; s4 < 4; ++s4) xoff[s4] = ((2 * s4 + h) ^ (m & 7)) * 8;
  const int mrow = m * 64;

  issueStage(0, 0);
  __syncthreads();

  const floatx16 kZero = {};

  for (int s = 0; s < 64; ++s) {
    const int b = s & 1;
    if (s + 1 < 64) issueStage(s + 1, b ^ 1);   // async DMA, drained by barrier

    const unsigned short* bhb = &Wbuf[hw][b][0][0];
    const unsigned short* blb = &Wbuf[hw][b][1][0];
    float cn[2];
    cn[0] = cnorm_g[hw * 4096 + s * 64 + m];
    cn[1] = cnorm_g[hw * 4096 + s * 64 + 32 + m];

#pragma unroll
    for (int j = 0; j < 2; ++j) {
      short8 bh[4], bl[4];
#pragma unroll
      for (int s4 = 0; s4 < 4; ++s4) {
        const int off = j * (32 * 64) + mrow + xoff[s4];
        bh[s4] = *(const short8*)(bhb + off);
        bl[s4] = *(const short8*)(blb + off);
      }
      // two interleaved 12-MFMA chains (set0 / set1)
      floatx16 a0, a1;
      a0 = MFMA(ah[0][0], bh[0], kZero);
      a1 = MFMA(ah[1][0], bh[0], kZero);
#pragma unroll
      for (int s4 = 1; s4 < 4; ++s4) {
        a0 = MFMA(ah[0][s4], bh[s4], a0);
        a1 = MFMA(ah[1][s4], bh[s4], a1);
      }
#pragma unroll
      for (int s4 = 0; s4 < 4; ++s4) {
        a0 = MFMA(al[0][s4], bh[s4], a0);
        a1 = MFMA(al[1][s4], bh[s4], a1);
      }
#pragma unroll
      for (int s4 = 0; s4 < 4; ++s4) {
        a0 = MFMA(ah[0][s4], bl[s4], a0);
        a1 = MFMA(ah[1][s4], bl[s4], a1);
      }

      // packed-key argmin: key = (cn64 - 2 z.c) with low byte = chunk id.
      // keys are positive floats -> v_min_f32 orders correctly; ascending
      // chunk id in low bits = first-occurrence tie-break at 2^-9 precision.
      const unsigned int q = (unsigned int)(s * 2 + j);   // chunk in half <128
#pragma unroll
      for (int r = 0; r < 16; ++r) {
        const float d0 = __builtin_fmaf(-2.f, a0[r], cn[j]);
        const float d1 = __builtin_fmaf(-2.f, a1[r], cn[j]);
        kmin[0][r] = fminf(kmin[0][r],
            __uint_as_float((__float_as_uint(d0) & 0xFFFFFF00u) | q));
        kmin[1][r] = fminf(kmin[1][r],
            __uint_as_float((__float_as_uint(d1) & 0xFFFFFF00u) | q));
      }
    }
    __syncthreads();   // drains DMA (vmcnt) + guards buffer reuse
  }

  // ---- reduce over the 32 code-cols per row, carrying origin lane ----
#pragma unroll
  for (int set = 0; set < 2; ++set) {
#pragma unroll
    for (int r = 0; r < 16; ++r) {
      float kv = kmin[set][r];
      int mo = m;
#pragma unroll
      for (int mm = 1; mm < 32; mm <<= 1) {
        const float ov = __shfl_xor(kv, mm);
        const int   om = __shfl_xor(mo, mm);
        if (ov < kv || (ov == kv && om < mo)) { kv = ov; mo = om; }
      }
      // C/D layout: row = (r&3) + 8*(r>>2) + 4*h. One writer lane per row.
      const int mr = (r & 3) + 8 * (r >> 2) + 4 * h;
      if (m == mr) {
        const unsigned int kb = __float_as_uint(kv);
        tok_s[hw][tg * 64 + set * 32 + mr] = hw * 4096 + (int)(kb & 0xFFu) * 32 + mo;
        mind_s[hw][tg * 64 + set * 32 + mr] =
            __uint_as_float(kb & 0xFFFFFF00u) - 64.0f + znorm[set];
      }
    }
  }
  __syncthreads();

  float* counts = ws + WS_COUNTS;
  float* embsum = ws + WS_EMBSUM;

  // merge code-halves (strict '<' keeps half0 on ties), qe partial + counts
  if (tid < 128) {
    const float d0 = mind_s[0][tid], d1 = mind_s[1][tid];
    const int   i0 = tok_s[0][tid],  i1 = tok_s[1][tid];
    const bool t1 = d1 < d0;
    const float dm = t1 ? d1 : d0;
    const int   im = t1 ? i1 : i0;
    tok_s[0][tid] = im;
    float qe = dm;
#pragma unroll
    for (int mm = 32; mm >= 1; mm >>= 1) qe += __shfl_xor(qe, mm);
    if ((tid & 63) == 0) atomicAdd(ws + WS_QE, qe);
    atomicAdd(&counts[im], 1.0f);
  }
  __syncthreads();

  // segment-sum of z: wave-coalesced atomics (64 consecutive floats/instr)
#pragma unroll 4
  for (int t = 0; t < 32; ++t) {
    const int row = w * 32 + t;
    const int tk = tok_s[0][row];
    const float zv = z[(size_t)(tb + row) * D_DIM + lane];
    atomicAdd(&embsum[(size_t)tk * D_DIM + lane], zv);
  }
}

// ---------------------------------------------------------------------------
__global__ void vq_finalize_cs(const float* __restrict__ cluster_size,
                               float* __restrict__ ws, float* __restrict__ out)
{
  const int k = blockIdx.x * 256 + threadIdx.x;
  const float ncs = cluster_size[k] * DECAY + OMD * ws[WS_COUNTS + k];
  out[OUT_CS + k] = ncs;
  float s = ncs;
#pragma unroll
  for (int m = 32; m >= 1; m >>= 1) s += __shfl_xor(s, m);
  __shared__ float part[4];
  if ((threadIdx.x & 63) == 0) part[threadIdx.x >> 6] = s;
  __syncthreads();
  if (threadIdx.x == 0) {
    atomicAdd(ws + WS_NSUM, part[0] + part[1] + part[2] + part[3]);
    if (blockIdx.x == 0) out[OUT_QE] = ws[WS_QE] * (1.0f / N_TOK);
  }
}

__global__ void vq_finalize_w(const float* __restrict__ embed_avg,
                              const float* __restrict__ ws, float* __restrict__ out)
{
  const int idx = blockIdx.x * 256 + threadIdx.x;
  const int k = idx >> 6;
  const float nea = embed_avg[idx] * DECAY + OMD * ws[WS_EMBSUM + idx];
  out[OUT_EA + idx] = nea;
  const float n = ws[WS_NSUM];
  const float ncs = out[OUT_CS + k];
  const float sm = (ncs + EPS) / (n + K_CODE * EPS) * n;
  out[OUT_W + idx] = nea / sm;
}

// ---------------------------------------------------------------------------
extern "C" void kernel_launch(void* const* d_in, const int* in_sizes, int n_in,
                              void* d_out, int out_size, void* d_ws, size_t ws_size,
                              hipStream_t stream) {
  const float* z  = (const float*)d_in[0];
  const float* w  = (const float*)d_in[1];
  const float* cs = (const float*)d_in[2];
  const float* ea = (const float*)d_in[3];
  float* out = (float*)d_out;
  float* ws  = (float*)d_ws;

  (void)hipMemsetAsync(d_ws, 0, (size_t)WS_ZERO * sizeof(float), stream);

  vq_prep<<<K_CODE / 4, 256, 0, stream>>>(w, ws);
  vq_argmin<<<N_TOK / 128, 256, 0, stream>>>(z, ws);
  vq_finalize_cs<<<K_CODE / 256, 256, 0, stream>>>(cs, ws, out);
  vq_finalize_w<<<K_CODE * D_DIM / 256, 256, 0, stream>>>(ea, ws, out);
}

// Round 8
// 282.056 us; speedup vs baseline: 1.6201x; 1.0004x over previous
//
#include <hip/hip_runtime.h>
#include <type_traits>

#define N_TOK 65536
#define K_CODE 8192
#define D_DIM 64

constexpr float DECAY = 0.9f;
constexpr float OMD = 0.1f;   // 1 - DECAY
constexpr float EPS = 1e-5f;

// ---- output layout (floats), per reference return order ----
constexpr int OUT_QE = 0;
constexpr int OUT_W  = 1;
constexpr int OUT_CS = 1 + K_CODE * D_DIM;
constexpr int OUT_EA = OUT_CS + K_CODE;

// ---- workspace layout (floats) ----
constexpr int WS_QE     = 0;
constexpr int WS_NSUM   = 1;
constexpr int WS_COUNTS = 16;
constexpr int WS_EMBSUM = WS_COUNTS + K_CODE;
constexpr int WS_WHI    = WS_EMBSUM + K_CODE * D_DIM;   // ushort[K*64] bf16 hi, XOR-swizzled
constexpr int WS_WLO    = WS_WHI + K_CODE * D_DIM / 2;  // ushort[K*64] bf16 lo, XOR-swizzled
constexpr int WS_CNP    = WS_WLO + K_CODE * D_DIM / 2;  // uint[K]: bf16(cn+64) hi | lo<<16
constexpr int WS_ZERO   = WS_WHI;                       // floats to memset

typedef __attribute__((ext_vector_type(16))) float floatx16;
typedef __attribute__((ext_vector_type(8)))  short short8;
typedef __attribute__((ext_vector_type(8)))  __bf16 bf16x8;

// SFINAE hedge: mfma bf16 builtin takes v8bf16 on newer clang, v8i16 on older.
template <typename T, typename = void> struct mfma_takes : std::false_type {};
template <typename T>
struct mfma_takes<T, std::void_t<decltype(__builtin_amdgcn_mfma_f32_32x32x16_bf16(
    std::declval<T>(), std::declval<T>(), std::declval<floatx16>(), 0, 0, 0))>>
    : std::true_type {};

__device__ __forceinline__ floatx16 MFMA(short8 a, short8 b, floatx16 c) {
  if constexpr (mfma_takes<bf16x8>::value) {
    return __builtin_amdgcn_mfma_f32_32x32x16_bf16(
        __builtin_bit_cast(bf16x8, a), __builtin_bit_cast(bf16x8, b), c, 0, 0, 0);
  } else {
    return __builtin_amdgcn_mfma_f32_32x32x16_bf16(a, b, c, 0, 0, 0);
  }
}

__device__ __forceinline__ unsigned short bf16rne(float x) {
  unsigned int u = __float_as_uint(x);
  return (unsigned short)((u + 0x7FFFu + ((u >> 16) & 1u)) >> 16);
}

// async global->LDS 16B DMA (HW writes LDS at wave-uniform dst + lane*16)
__device__ __forceinline__ void gload_lds16(const unsigned short* g, unsigned short* l) {
#if defined(__has_builtin) && __has_builtin(__builtin_amdgcn_global_load_lds)
  typedef __attribute__((address_space(1))) void gvoid;
  typedef __attribute__((address_space(3))) void lvoid;
  __builtin_amdgcn_global_load_lds((gvoid*)g, (lvoid*)l, 16, 0, 0);
#else
  *(uint4*)l = *(const uint4*)g;   // sync fallback, correctness-equal
#endif
}

// ---------------------------------------------------------------------------
// Split W into bf16 hi/lo, stored XOR-SWIZZLED (granule g -> g^(k&7), stride
// 64 shorts) so global_load_lds's linear copy lands conflict-managed in LDS.
// Pack bf16 hi/lo of (||c||^2 + 64) per code (positive-key offset folded).
__global__ void vq_prep(const float* __restrict__ w, float* __restrict__ ws) {
  const int tid = threadIdx.x;
  const int d = tid & 63;                 // dim
  const int k = blockIdx.x * 4 + (tid >> 6);
  const float v = w[(size_t)k * D_DIM + d];
  const unsigned short h = bf16rne(v);
  const float hf = __uint_as_float((unsigned int)h << 16);
  const unsigned short l = bf16rne(v - hf);
  unsigned short* whi = (unsigned short*)(ws + WS_WHI);
  unsigned short* wlo = (unsigned short*)(ws + WS_WLO);
  const int pos = k * D_DIM + (((d >> 3) ^ (k & 7)) * 8) + (d & 7);
  whi[pos] = h;
  wlo[pos] = l;
  float s = v * v;
#pragma unroll
  for (int m = 32; m >= 1; m >>= 1) s += __shfl_xor(s, m);
  if (d == 0) {
    const float cn64 = s + 64.0f;
    const unsigned short ch = bf16rne(cn64);
    const float chf = __uint_as_float((unsigned int)ch << 16);
    const unsigned short cl = bf16rne(cn64 - chf);
    ((unsigned int*)(ws + WS_CNP))[k] = (unsigned int)ch | ((unsigned int)cl << 16);
  }
}

// ---------------------------------------------------------------------------
// Fused split-bf16 MFMA distance + argmin + segment-sum scatter.
// Block = 8 waves = 4 token-groups(32 tok) x 2 code-halves; 128 tokens/block.
// Grid 512, 2 blocks/CU, 16 waves/CU = 4 waves/SIMD (the R7 fix: occupancy).
// Stage = 32 codes, double-buffered (32 KB), filled by global_load_lds.
// Per stage per wave: 13 MFMAs — chain head folds (||c||^2+64) via A=1.0 at
// k-slots 0,1 and B=packed cn hi/lo (same-slot => k-permutation-proof), then
// 12 accumulate (-2zh)*ch + (-2zl)*ch + (-2zh)*cl. acc[r] IS the positive
// distance+64; epilogue = 2 VALU/elem via packed key (low byte = stage id,
// giving first-occurrence tie-break).
__global__ __launch_bounds__(512, 4) void vq_argmin(
    const float* __restrict__ z, float* __restrict__ ws)
{
  __shared__ __align__(16) unsigned short Wbuf[2][2][2][32 * 64]; // [half][buf][plane]
  __shared__ float mind_s[2][128];
  __shared__ int   tok_s[2][128];

  const int tid  = threadIdx.x;
  const int w    = tid >> 6;    // wave 0..7
  const int lane = tid & 63;
  const int m    = lane & 31;   // A row (token) / B col (code) in tile
  const int h    = lane >> 5;   // k-half selector
  const int tg   = w & 3;       // token group (32 tokens)
  const int hw   = w >> 2;      // code half (4096 codes)
  const int tb   = blockIdx.x * 128;

  const unsigned short* whi = (const unsigned short*)(ws + WS_WHI);
  const unsigned short* wlo = (const unsigned short*)(ws + WS_WLO);
  const unsigned int*   cnp = (const unsigned int*)(ws + WS_CNP);

  // ---- A fragments: bf16 hi/lo split of -2*z for this wave's 32 rows ----
  short8 ah[4], al[4];
  float znorm = 0.f;
  {
    const float* zrow = z + (size_t)(tb + tg * 32 + m) * D_DIM + 8 * h;
#pragma unroll
    for (int s4 = 0; s4 < 4; ++s4) {
      const float4 v0 = *(const float4*)(zrow + 16 * s4);
      const float4 v1 = *(const float4*)(zrow + 16 * s4 + 4);
      const float vals[8] = {v0.x, v0.y, v0.z, v0.w, v1.x, v1.y, v1.z, v1.w};
#pragma unroll
      for (int j = 0; j < 8; ++j) {
        const float x = vals[j];
        znorm += x * x;
        const float y = -2.0f * x;
        const unsigned short hb = bf16rne(y);
        const float hf = __uint_as_float((unsigned int)hb << 16);
        const unsigned short lb = bf16rne(y - hf);
        ah[s4][j] = (short)hb;
        al[s4][j] = (short)lb;
      }
    }
    znorm += __shfl_xor(znorm, 32);   // other k-half of the same token row
  }

  // A operand for the cn-fold chain head: bf16 1.0 at k-slots 0,1 on h==0
  short8 acn;
  {
    uint4 ab = {0u, 0u, 0u, 0u};
    ab.x = (h == 0) ? 0x3F803F80u : 0u;
    acn = __builtin_bit_cast(short8, ab);
  }

  float kmin[16];
#pragma unroll
  for (int r = 0; r < 16; ++r) kmin[r] = 3.4e38f;

  // ---- DMA staging: stage = 16 KB as 16 x 1KB segments; wave w moves
  // segments 2w, 2w+1. seg t: half=t>>3, plane=(t>>2)&1, quarter=t&3.
  auto issueStage = [&](int s, int b) {
#pragma unroll
    for (int i = 0; i < 2; ++i) {
      const int t = w * 2 + i;
      const int half = t >> 3, plane = (t >> 2) & 1, seg = t & 3;
      const unsigned short* src = (plane ? wlo : whi)
          + ((size_t)half * 4096 + (size_t)s * 32) * D_DIM + seg * 512 + lane * 8;
      unsigned short* dst = &Wbuf[half][b][plane][seg * 512];  // wave-uniform
      gload_lds16(src, dst);
    }
  };

  // precomputed per-lane B read offsets (shorts) into the pre-swizzled rows
  int xoff[4];
#pragma unroll
  for (int s4 = 0; s4 < 4; ++s4) xoff[s4] = ((2 * s4 + h) ^ (m & 7)) * 8;
  const int mrow = m * 64;

  issueStage(0, 0);
  __syncthreads();

  const floatx16 kZero = {};

  for (int s = 0; s < 128; ++s) {
    const int b = s & 1;
    const unsigned int cnq = cnp[hw * 4096 + s * 32 + m];   // L2-hot
    if (s + 1 < 128) issueStage(s + 1, b ^ 1);              // async DMA

    short8 bh[4], bl[4];
#pragma unroll
    for (int s4 = 0; s4 < 4; ++s4) {
      bh[s4] = *(const short8*)&Wbuf[hw][b][0][mrow + xoff[s4]];
      bl[s4] = *(const short8*)&Wbuf[hw][b][1][mrow + xoff[s4]];
    }
    short8 bcn;
    {
      uint4 bb = {0u, 0u, 0u, 0u};
      bb.x = (h == 0) ? cnq : 0u;
      bcn = __builtin_bit_cast(short8, bb);
    }

    floatx16 acc = MFMA(acn, bcn, kZero);   // acc = ||c||^2 + 64  (per col)
#pragma unroll
    for (int s4 = 0; s4 < 4; ++s4) acc = MFMA(ah[s4], bh[s4], acc);  // -2zh.ch
#pragma unroll
    for (int s4 = 0; s4 < 4; ++s4) acc = MFMA(al[s4], bh[s4], acc);  // -2zl.ch
#pragma unroll
    for (int s4 = 0; s4 < 4; ++s4) acc = MFMA(ah[s4], bl[s4], acc);  // -2zh.cl

    // packed-key argmin: acc[r] > 0; low byte := stage id (ascending =>
    // first-occurrence tie-break at 2^-9 relative precision)
#pragma unroll
    for (int r = 0; r < 16; ++r) {
      kmin[r] = fminf(kmin[r],
          __uint_as_float((__float_as_uint(acc[r]) & 0xFFFFFF00u) | (unsigned)s));
    }
    __syncthreads();   // drains DMA (vmcnt) + guards buffer reuse
  }

  // ---- reduce over the 32 code-cols per row, carrying origin lane ----
#pragma unroll
  for (int r = 0; r < 16; ++r) {
    float kv = kmin[r];
    int mo = m;
#pragma unroll
    for (int mm = 1; mm < 32; mm <<= 1) {
      const float ov = __shfl_xor(kv, mm);
      const int   om = __shfl_xor(mo, mm);
      if (ov < kv || (ov == kv && om < mo)) { kv = ov; mo = om; }
    }
    // C/D layout: row = (r&3) + 8*(r>>2) + 4*h. One writer lane per row.
    const int mr = (r & 3) + 8 * (r >> 2) + 4 * h;
    if (m == mr) {
      const unsigned int kb = __float_as_uint(kv);
      tok_s[hw][tg * 32 + mr] = hw * 4096 + (int)(kb & 0xFFu) * 32 + mo;
      mind_s[hw][tg * 32 + mr] =
          __uint_as_float(kb & 0xFFFFFF00u) - 64.0f + znorm;
    }
  }
  __syncthreads();

  float* counts = ws + WS_COUNTS;
  float* embsum = ws + WS_EMBSUM;

  // merge code-halves (strict '<' keeps half0 on ties), qe partial + counts
  if (tid < 128) {
    const float d0 = mind_s[0][tid], d1 = mind_s[1][tid];
    const int   i0 = tok_s[0][tid],  i1 = tok_s[1][tid];
    const bool t1 = d1 < d0;
    const float dm = t1 ? d1 : d0;
    const int   im = t1 ? i1 : i0;
    tok_s[0][tid] = im;
    float qe = dm;
#pragma unroll
    for (int mm = 32; mm >= 1; mm >>= 1) qe += __shfl_xor(qe, mm);
    if ((tid & 63) == 0) atomicAdd(ws + WS_QE, qe);
    atomicAdd(&counts[im], 1.0f);
  }
  __syncthreads();

  // segment-sum of z: wave-coalesced atomics (64 consecutive floats/instr)
#pragma unroll 4
  for (int t = 0; t < 16; ++t) {
    const int row = w * 16 + t;
    const int tk = tok_s[0][row];
    const float zv = z[(size_t)(tb + row) * D_DIM + lane];
    atomicAdd(&embsum[(size_t)tk * D_DIM + lane], zv);
  }
}

// ---------------------------------------------------------------------------
__global__ void vq_finalize_cs(const float* __restrict__ cluster_size,
                               float* __restrict__ ws, float* __restrict__ out)
{
  const int k = blockIdx.x * 256 + threadIdx.x;
  const float ncs = cluster_size[k] * DECAY + OMD * ws[WS_COUNTS + k];
  out[OUT_CS + k] = ncs;
  float s = ncs;
#pragma unroll
  for (int m = 32; m >= 1; m >>= 1) s += __shfl_xor(s, m);
  __shared__ float part[4];
  if ((threadIdx.x & 63) == 0) part[threadIdx.x >> 6] = s;
  __syncthreads();
  if (threadIdx.x == 0) {
    atomicAdd(ws + WS_NSUM, part[0] + part[1] + part[2] + part[3]);
    if (blockIdx.x == 0) out[OUT_QE] = ws[WS_QE] * (1.0f / N_TOK);
  }
}

__global__ void vq_finalize_w(const float* __restrict__ embed_avg,
                              const float* __restrict__ ws, float* __restrict__ out)
{
  const int idx = blockIdx.x * 256 + threadIdx.x;
  const int k = idx >> 6;
  const float nea = embed_avg[idx] * DECAY + OMD * ws[WS_EMBSUM + idx];
  out[OUT_EA + idx] = nea;
  const float n = ws[WS_NSUM];
  const float ncs = out[OUT_CS + k];
  const float sm = (ncs + EPS) / (n + K_CODE * EPS) * n;
  out[OUT_W + idx] = nea / sm;
}

// ---------------------------------------------------------------------------
extern "C" void kernel_launch(void* const* d_in, const int* in_sizes, int n_in,
                              void* d_out, int out_size, void* d_ws, size_t ws_size,
                              hipStream_t stream) {
  const float* z  = (const float*)d_in[0];
  const float* w  = (const float*)d_in[1];
  const float* cs = (const float*)d_in[2];
  const float* ea = (const float*)d_in[3];
  float* out = (float*)d_out;
  float* ws  = (float*)d_ws;

  (void)hipMemsetAsync(d_ws, 0, (size_t)WS_ZERO * sizeof(float), stream);

  vq_prep<<<K_CODE / 4, 256, 0, stream>>>(w, ws);
  vq_argmin<<<N_TOK / 128, 512, 0, stream>>>(z, ws);
  vq_finalize_cs<<<K_CODE / 256, 256, 0, stream>>>(cs, ws, out);
  vq_finalize_w<<<K_CODE * D_DIM / 256, 256, 0, stream>>>(ea, ws, out);
}